// Round 13
// baseline (196.173 us; speedup 1.0000x reference)
//
#include <hip/hip_runtime.h>

typedef short bf16x8 __attribute__((ext_vector_type(8)));   // 8 bf16 in 4 VGPRs
typedef float f32x4  __attribute__((ext_vector_type(4)));
typedef float f32x2  __attribute__((ext_vector_type(2)));
typedef int   i32x4  __attribute__((ext_vector_type(4)));
typedef unsigned int u32x2 __attribute__((ext_vector_type(2)));

#define DEV static __device__ __forceinline__
#define LOG2E 1.4426950408889634f

DEV float bfu_to_f(unsigned short s) { return __builtin_bit_cast(float, (unsigned int)s << 16); }
DEV unsigned short f_to_bf(float f) {                 // RNE fp32 -> bf16
  unsigned int u = __builtin_bit_cast(unsigned int, f);
  u += 0x7fffu + ((u >> 16) & 1u);
  return (unsigned short)(u >> 16);
}
DEV unsigned int pack_bf_rne(float lo, float hi) {
  return (unsigned int)f_to_bf(lo) | ((unsigned int)f_to_bf(hi) << 16);
}
// guaranteed-native exp2 (single v_exp_f32)
DEV float nexp2(float x) {
#if __has_builtin(__builtin_amdgcn_exp2f)
  return __builtin_amdgcn_exp2f(x);
#else
  return exp2f(x);
#endif
}
// fp8 e4m3 pack/unpack (OCP on gfx950). Selector MUST be an immediate -> template param.
template<bool HI> DEV unsigned int pk_fp8(float a, float b, unsigned int old) {
  return __builtin_amdgcn_cvt_pk_fp8_f32(a, b, old, HI);
}
template<int W> DEV f32x2 upk_fp8(unsigned int w) {
  auto r = __builtin_amdgcn_cvt_pk_f32_fp8(w, W);
  f32x2 o; o[0] = r[0]; o[1] = r[1]; return o;
}

// dtype discriminator: adj[0][0] == 1.0 exactly. fp32 word0 == 0x3F800000;
// bf16 word0 low halfword = 0x3F80 != 0 -> never equal.
DEV bool detect_f32(const void* adj) { return ((const float*)adj)[0] == 1.0f; }

template<bool F32> DEV float ldS(const void* p, size_t i) {
  if constexpr (F32) return ((const float*)p)[i];
  else               return bfu_to_f(((const unsigned short*)p)[i]);
}
template<bool F32> DEV void ld8f(const void* p, size_t i, float* o) {
  if constexpr (F32) {
    const float* f = (const float*)p + i;
    f32x4 a = *(const f32x4*)f, b = *(const f32x4*)(f + 4);
    o[0]=a[0]; o[1]=a[1]; o[2]=a[2]; o[3]=a[3];
    o[4]=b[0]; o[5]=b[1]; o[6]=b[2]; o[7]=b[3];
  } else {
    i32x4 w = *(const i32x4*)((const unsigned short*)p + i);
#pragma unroll
    for (int k = 0; k < 4; ++k) {
      unsigned int u = (unsigned int)w[k];
      o[2*k]   = __builtin_bit_cast(float, u << 16);
      o[2*k+1] = __builtin_bit_cast(float, u & 0xffff0000u);
    }
  }
}
template<bool F32> DEV bf16x8 ldfrag(const void* p, size_t i) {
  if constexpr (F32) {
    float o[8]; ld8f<true>(p, i, o);
    union { bf16x8 v; unsigned short u[8]; } r;
#pragma unroll
    for (int k = 0; k < 8; ++k) r.u[k] = f_to_bf(o[k]);
    return r.v;
  } else {
    return __builtin_bit_cast(bf16x8, *(const i32x4*)((const unsigned short*)p + i));
  }
}

// ---------------- Kernel 1: hT[(b*4+hh)*32+d][n] = (x@W^T) transposed, fp8 ----------
template<bool F32> DEV void k_h_body(const void* __restrict__ x, const void* __restrict__ W,
                                     unsigned char* __restrict__ hT,
                                     unsigned short (&t_s)[16][136]) {
  const int tid = threadIdx.x, lane = tid & 63, wave = tid >> 6;
  const int nt = blockIdx.x >> 3, ct = blockIdx.x & 7;    // 128 nt x 8 ct
  const int m = lane & 15, q = lane >> 4;
  bf16x8 wf[4];
#pragma unroll
  for (int k = 0; k < 4; ++k)
    wf[k] = ldfrag<F32>(W, (size_t)(ct * 16 + m) * 128 + q * 8 + k * 32);
#pragma unroll
  for (int s = 0; s < 2; ++s) {
    const int nsub = wave * 2 + s;
    const size_t xr = (size_t)(nt * 128 + nsub * 16 + m) * 128 + q * 8;
    f32x4 acc = {0.f, 0.f, 0.f, 0.f};
#pragma unroll
    for (int k = 0; k < 4; ++k)
      acc = __builtin_amdgcn_mfma_f32_16x16x32_bf16(ldfrag<F32>(x, xr + k * 32), wf[k],
                                                    acc, 0, 0, 0);
    u32x2 w2; w2[0] = pack_bf_rne(acc[0], acc[1]); w2[1] = pack_bf_rne(acc[2], acc[3]);
    *(u32x2*)&t_s[m][nsub * 16 + q * 4] = w2;
  }
  __syncthreads();
  const int row = tid >> 4, c8 = tid & 15;
  const int chg = ct * 16 + row, hh = chg >> 5, dloc = chg & 31;
  const int ng = nt * 128 + c8 * 8, b = ng >> 11, nl = ng & 2047;
  i32x4 v = *(const i32x4*)&t_s[row][c8 * 8];       // 8 bf16
  float f[8];
#pragma unroll
  for (int k = 0; k < 4; ++k) {
    unsigned int u = (unsigned int)v[k];
    f[2*k]   = __builtin_bit_cast(float, u << 16);
    f[2*k+1] = __builtin_bit_cast(float, u & 0xffff0000u);
  }
  u32x2 o;
  o[0] = pk_fp8<true>(f[2], f[3], pk_fp8<false>(f[0], f[1], 0u));
  o[1] = pk_fp8<true>(f[6], f[7], pk_fp8<false>(f[4], f[5], 0u));
  *(u32x2*)(hT + ((size_t)((b * 4 + hh) * 32 + dloc)) * 2048 + nl) = o;
}
__global__ __launch_bounds__(256) void k_h(const void* x, const void* W,
                                           unsigned char* hT, const void* adj) {
  __shared__ __align__(16) unsigned short t_s[16][136];   // shared across both instantiations
  if (detect_f32(adj)) k_h_body<true>(x, W, hT, t_s); else k_h_body<false>(x, W, hT, t_s);
}

// ---------------- Kernel 1b: src/dst projections (pre-scaled by log2e) ----------------
template<bool F32> DEV void k_sd_body(const unsigned char* __restrict__ hT,
                                      const void* __restrict__ a_src, const void* __restrict__ a_dst,
                                      float* __restrict__ srcv, float* __restrict__ dstv) {
  const int t = blockIdx.x * 256 + threadIdx.x;      // (bh, n), n fastest
  const int n = t & 2047, bh = t >> 11, hh = bh & 3;
  const unsigned char* col = hT + (size_t)bh * 32 * 2048 + n;
  float s = 0.f, d = 0.f;
#pragma unroll
  for (int dd = 0; dd < 32; ++dd) {
    const float v = __builtin_amdgcn_cvt_f32_fp8((int)col[(size_t)dd * 2048], 0);
    s += v * ldS<F32>(a_src, hh * 32 + dd);
    d += v * ldS<F32>(a_dst, hh * 32 + dd);
  }
  srcv[t] = s * LOG2E; dstv[t] = d * LOG2E;          // exp(x) = exp2(x*log2e)
}
__global__ __launch_bounds__(256) void k_sd(const unsigned char* hT, const void* a_src,
                                            const void* a_dst, float* srcv, float* dstv,
                                            const void* adj) {
  if (detect_f32(adj)) k_sd_body<true>(hT, a_src, a_dst, srcv, dstv);
  else                 k_sd_body<false>(hT, a_src, a_dst, srcv, dstv);
}

// ---------------- Kernel 2: fp8 paired-bh LDS double-buffered flash GAT attention ----
// Block = 512 thr (8 waves) = 2 bh x one i64-tile. adj staged once (shared), vt + dst'
// per sub; all double-buffered, ONE barrier per 128-j chunk. adj & V^T stored as fp8
// e4m3 in LDS; PV + den on mfma_f32_16x16x32_fp8_fp8 (den = ones-A, same rounded P).
// Row stride 144 B: 16B-aligned b128 staging writes, <=2-way (free) b64 read conflicts.
// LDS 38.9 KB -> 4 blocks/CU = 32 waves/CU (2x R11 occupancy).
struct SmemAttn {
  unsigned char adj[2][64][144];     // 18432 B  [buf][i-local][j]
  unsigned char vt[2][2][32][144];   // 18432 B  [buf][sub][d][j]
  float dst[2][2][128];              //  2048 B  [buf][sub][j-chunk]
};                                   // 38912 B

template<bool F32> DEV void k_attn_body(SmemAttn& sm, const void* __restrict__ adjv,
                                        const unsigned char* __restrict__ hT,
                                        const float* __restrict__ srcv,
                                        const float* __restrict__ dstv,
                                        unsigned short* __restrict__ ao) {
  const int tid = threadIdx.x, lane = tid & 63, wave = tid >> 6;
  const int bhp = blockIdx.x & 15, i64 = blockIdx.x >> 4;  // bhp-fast: 16 blocks share adj tile
  const int sub = wave >> 2, w4 = wave & 3;
  const int bh = bhp * 2 + sub;
  const int b = bh >> 2, hh = bh & 3;
  const int m = lane & 15, q = lane >> 4;
  const int i0 = i64 * 64;
  const int il = w4 * 16 + m;                              // lane's local i-row (0..63)

  // staging maps
  const int arow = tid >> 3, acol = (tid & 7) * 16;        // adj: 64 rows x 8 thr x 16 elems
  const int vsub = tid >> 8, vd = (tid >> 3) & 31, vcol = (tid & 7) * 16;  // vt: 16B/thread
  const bool dstg = (tid & 7) == 0;
  const int dk = tid >> 3, dsub = dk >> 5, dj = (dk & 31) * 4;

  f32x4 fr[4];   // F32 adj prefetch (16 floats)
  i32x4 br[2];   // BF16 adj prefetch (16 bf16)
  i32x4 vr;      // V^T prefetch (16 fp8)
  f32x4 dr;      // dst chunk prefetch (stagers only)

  // pack 16 staged adj values -> 16 fp8 (i32x4)
  auto pack_adj = [&](i32x4& w) {
    if constexpr (F32) {
#pragma unroll
      for (int p = 0; p < 4; ++p)
        w[p] = (int)pk_fp8<true>(fr[p][2], fr[p][3], pk_fp8<false>(fr[p][0], fr[p][1], 0u));
    } else {
#pragma unroll
      for (int p = 0; p < 4; ++p) {
        unsigned int u0 = (unsigned int)br[p >> 1][(p & 1) * 2];
        unsigned int u1 = (unsigned int)br[p >> 1][(p & 1) * 2 + 1];
        const float f0 = __builtin_bit_cast(float, u0 << 16);
        const float f1 = __builtin_bit_cast(float, u0 & 0xffff0000u);
        const float f2 = __builtin_bit_cast(float, u1 << 16);
        const float f3 = __builtin_bit_cast(float, u1 & 0xffff0000u);
        w[p] = (int)pk_fp8<true>(f2, f3, pk_fp8<false>(f0, f1, 0u));
      }
    }
  };

  // ---- prologue: stage chunk 0 into buf 0 ----
  {
    const size_t ga = (size_t)(i0 + arow) * 2048 + acol;
    if constexpr (F32) {
#pragma unroll
      for (int p = 0; p < 4; ++p) fr[p] = *(const f32x4*)((const float*)adjv + ga + p * 4);
    } else {
      br[0] = *(const i32x4*)((const unsigned short*)adjv + ga);
      br[1] = *(const i32x4*)((const unsigned short*)adjv + ga + 8);
    }
    vr = *(const i32x4*)(hT + ((size_t)((bhp * 2 + vsub) * 32 + vd)) * 2048 + vcol);
    i32x4 w; pack_adj(w);
    *(i32x4*)&sm.adj[0][arow][acol] = w;
    *(i32x4*)&sm.vt[0][vsub][vd][vcol] = vr;
    if (dstg)
      *(f32x4*)&sm.dst[0][dsub][dj] = *(const f32x4*)(dstv + (size_t)(bhp * 2 + dsub) * 2048 + dj);
  }
  __syncthreads();

  const float src_i = srcv[bh * 2048 + i0 + il];
  const f32x2 src2 = {src_i, src_i};
  f32x4 acc0 = {0.f,0.f,0.f,0.f}, acc1 = {0.f,0.f,0.f,0.f};
  f32x4 acc2 = {0.f,0.f,0.f,0.f};                          // den accumulator (ones-A MFMA)
  const long Aones = 0x3838383838383838L;                  // 8x fp8 e4m3 1.0

  for (int c = 0; c < 16; ++c) {
    const int cb = c & 1;
    const bool pf = (c < 15);
    if (pf) {                                   // issue chunk c+1 loads (coalesced)
      const int j1 = (c + 1) * 128;
      const size_t ga = (size_t)(i0 + arow) * 2048 + j1 + acol;
      if constexpr (F32) {
#pragma unroll
        for (int p = 0; p < 4; ++p) fr[p] = *(const f32x4*)((const float*)adjv + ga + p * 4);
      } else {
        br[0] = *(const i32x4*)((const unsigned short*)adjv + ga);
        br[1] = *(const i32x4*)((const unsigned short*)adjv + ga + 8);
      }
      vr = *(const i32x4*)(hT + ((size_t)((bhp * 2 + vsub) * 32 + vd)) * 2048 + j1 + vcol);
      if (dstg)
        dr = *(const f32x4*)(dstv + (size_t)(bhp * 2 + dsub) * 2048 + j1 + dj);
    }
    // ---- compute 4 x 32-j on buf cb (packed-f32 scores, fp8 MFMA) ----
#pragma unroll
    for (int jc = 0; jc < 4; ++jc) {
      const int jq = jc * 32 + q * 8;
      u32x2 aw = *(const u32x2*)&sm.adj[cb][il][jq];               // 8 fp8
      f32x4 d0 = *(const f32x4*)&sm.dst[cb][sub][jq];
      f32x4 d1 = *(const f32x4*)&sm.dst[cb][sub][jq + 4];
      long A0 = *(const long*)&sm.vt[cb][sub][m][jq];              // V^T row d=m
      long A1 = *(const long*)&sm.vt[cb][sub][16 + m][jq];         // d=m+16
      // 4 fp8 pairs, immediate selectors (manually unrolled)
      f32x2 av0 = upk_fp8<0>(aw[0]), av1 = upk_fp8<1>(aw[0]);
      f32x2 av2 = upk_fp8<0>(aw[1]), av3 = upk_fp8<1>(aw[1]);
      f32x2 dv0; dv0[0] = d0[0]; dv0[1] = d0[1];
      f32x2 dv1; dv1[0] = d0[2]; dv1[1] = d0[3];
      f32x2 dv2; dv2[0] = d1[0]; dv2[1] = d1[1];
      f32x2 dv3; dv3[0] = d1[2]; dv3[1] = d1[3];
      f32x2 sv0 = src2 + dv0, sv1 = src2 + dv1, sv2 = src2 + dv2, sv3 = src2 + dv3;
      f32x2 lv0 = __builtin_elementwise_max(sv0, 0.2f * sv0);
      f32x2 lv1 = __builtin_elementwise_max(sv1, 0.2f * sv1);
      f32x2 lv2 = __builtin_elementwise_max(sv2, 0.2f * sv2);
      f32x2 lv3 = __builtin_elementwise_max(sv3, 0.2f * sv3);
      f32x2 ev0, ev1, ev2, ev3;
      ev0[0] = nexp2(lv0[0]); ev0[1] = nexp2(lv0[1]);
      ev1[0] = nexp2(lv1[0]); ev1[1] = nexp2(lv1[1]);
      ev2[0] = nexp2(lv2[0]); ev2[1] = nexp2(lv2[1]);
      ev3[0] = nexp2(lv3[0]); ev3[1] = nexp2(lv3[1]);
      f32x2 pv0 = av0 * ev0, pv1 = av1 * ev1, pv2 = av2 * ev2, pv3 = av3 * ev3;
      u32x2 bp;
      bp[0] = pk_fp8<true>(pv1[0], pv1[1], pk_fp8<false>(pv0[0], pv0[1], 0u));
      bp[1] = pk_fp8<true>(pv3[0], pv3[1], pk_fp8<false>(pv2[0], pv2[1], 0u));
      const long B = __builtin_bit_cast(long, bp);
      acc0 = __builtin_amdgcn_mfma_f32_16x16x32_fp8_fp8(A0, B, acc0, 0, 0, 0);
      acc1 = __builtin_amdgcn_mfma_f32_16x16x32_fp8_fp8(A1, B, acc1, 0, 0, 0);
      acc2 = __builtin_amdgcn_mfma_f32_16x16x32_fp8_fp8(Aones, B, acc2, 0, 0, 0);
    }
    if (pf) {                                   // write chunk c+1 into the other buffer
      const int nb = cb ^ 1;
      i32x4 w; pack_adj(w);
      *(i32x4*)&sm.adj[nb][arow][acol] = w;
      *(i32x4*)&sm.vt[nb][vsub][vd][vcol] = vr;
      if (dstg) *(f32x4*)&sm.dst[nb][dsub][dj] = dr;
    }
    __syncthreads();
  }

  // den for row i=m is acc2[r] (identical for all r, all q) -- no shuffles needed.
  const float inv = 1.f / fmaxf(acc2[0], 1e-20f);

  // D: col = m = i, row = q*4+r = d. Lane writes channels q*4..+3 and 16+q*4..+3.
  unsigned short* op = ao + ((size_t)(b * 2048) + i0 + il) * 128 + hh * 32 + q * 4;
  u32x2 w0, w1;
  w0[0] = pack_bf_rne(acc0[0] * inv, acc0[1] * inv);
  w0[1] = pack_bf_rne(acc0[2] * inv, acc0[3] * inv);
  w1[0] = pack_bf_rne(acc1[0] * inv, acc1[1] * inv);
  w1[1] = pack_bf_rne(acc1[2] * inv, acc1[3] * inv);
  *(u32x2*)op        = w0;
  *(u32x2*)(op + 16) = w1;
}
__global__ __launch_bounds__(512, 8) void k_attn(const void* adj, const unsigned char* hT,
                                                 const float* srcv, const float* dstv,
                                                 unsigned short* ao) {
  __shared__ __align__(16) SmemAttn sm;          // ONE allocation for both instantiations
  if (detect_f32(adj)) k_attn_body<true>(sm, adj, hT, srcv, dstv, ao);
  else                 k_attn_body<false>(sm, adj, hT, srcv, dstv, ao);
}

// ---------------- Kernel 3: y = LN(ao @ Wo^T + bo + x) ----------------
template<bool F32> DEV void k_out_body(const unsigned short* __restrict__ ao,
                                       const void* __restrict__ Wo, const void* __restrict__ bo,
                                       const void* __restrict__ x, const void* __restrict__ gamma,
                                       const void* __restrict__ beta, void* __restrict__ out,
                                       float (&y_s)[16][132]) {
  const int tid = threadIdx.x, lane = tid & 63, wave = tid >> 6;
  const int m = lane & 15, q = lane >> 4;
  const int rbase = blockIdx.x * 16;
  bf16x8 af[4];
#pragma unroll
  for (int k = 0; k < 4; ++k)
    af[k] = ldfrag<false>(ao, ((size_t)(rbase + m)) * 128 + q * 8 + k * 32);
  f32x4 acc[2] = {{0.f,0.f,0.f,0.f},{0.f,0.f,0.f,0.f}};
#pragma unroll
  for (int ct = 0; ct < 2; ++ct) {
    const size_t wrow = (size_t)(wave * 32 + ct * 16 + m) * 128 + q * 8;
#pragma unroll
    for (int k = 0; k < 4; ++k)
      acc[ct] = __builtin_amdgcn_mfma_f32_16x16x32_bf16(af[k], ldfrag<F32>(Wo, wrow + k * 32),
                                                        acc[ct], 0, 0, 0);
  }
#pragma unroll
  for (int ct = 0; ct < 2; ++ct) {
    const int c = wave * 32 + ct * 16 + m;
    const float bov = ldS<F32>(bo, c);
#pragma unroll
    for (int r = 0; r < 4; ++r) {
      const int row = q * 4 + r;
      y_s[row][c] = acc[ct][r] + bov + ldS<F32>(x, (size_t)(rbase + row) * 128 + c);
    }
  }
  __syncthreads();
  const int r = tid >> 4, c16 = tid & 15;
  float vals[8], sum = 0.f, sq = 0.f;
#pragma unroll
  for (int k = 0; k < 8; ++k) {
    const float v = y_s[r][c16 * 8 + k];
    vals[k] = v; sum += v; sq += v * v;
  }
#pragma unroll
  for (int msk = 1; msk < 16; msk <<= 1) {
    sum += __shfl_xor(sum, msk, 16);
    sq  += __shfl_xor(sq,  msk, 16);
  }
  const float mu  = sum * (1.f / 128.f);
  const float var = fmaxf(sq * (1.f / 128.f) - mu * mu, 0.f);
  const float rstd = rsqrtf(var + 1e-5f);
  float o[8];
#pragma unroll
  for (int k = 0; k < 8; ++k) {
    const int c = c16 * 8 + k;
    o[k] = (vals[k] - mu) * rstd * ldS<F32>(gamma, c) + ldS<F32>(beta, c);
  }
  const size_t obase = (size_t)(rbase + r) * 128 + c16 * 8;
  if constexpr (F32) {
    float* op = (float*)out + obase;
    f32x4 w0 = {o[0],o[1],o[2],o[3]}, w1 = {o[4],o[5],o[6],o[7]};
    *(f32x4*)op = w0; *(f32x4*)(op + 4) = w1;
  } else {
    union { unsigned short u[8]; i32x4 v; } ob;
#pragma unroll
    for (int k = 0; k < 8; ++k) ob.u[k] = f_to_bf(o[k]);
    *(i32x4*)((unsigned short*)out + obase) = ob.v;
  }
}
__global__ __launch_bounds__(256) void k_out(const unsigned short* ao, const void* Wo,
                                             const void* bo, const void* x, const void* gamma,
                                             const void* beta, void* out, const void* adj) {
  __shared__ __align__(16) float y_s[16][132];   // shared across both instantiations
  if (detect_f32(adj)) k_out_body<true>(ao, Wo, bo, x, gamma, beta, out, y_s);
  else                 k_out_body<false>(ao, Wo, bo, x, gamma, beta, out, y_s);
}

// ---------------- launch ----------------
extern "C" void kernel_launch(void* const* d_in, const int* in_sizes, int n_in,
                              void* d_out, int out_size, void* d_ws, size_t ws_size,
                              hipStream_t stream) {
  const void* x     = d_in[0];
  const void* adj   = d_in[1];
  const void* W     = d_in[2];
  const void* a_src = d_in[3];
  const void* a_dst = d_in[4];
  const void* Wo    = d_in[5];
  const void* bo    = d_in[6];
  const void* gamma = d_in[7];
  const void* beta  = d_in[8];

  char* ws = (char*)d_ws;
  unsigned char*  hT_ws  = (unsigned char*)ws;               // 2,097,152 B  fp8 hT (BH*32, N)
  unsigned short* ao_ws  = (unsigned short*)(ws + 2097152);  // 4,194,304 B  bf16 attn out
  float*          src_ws = (float*)(ws + 6291456);           // 262,144 B    fp32 src' (BH,N)
  float*          dst_ws = (float*)(ws + 6553600);           // 262,144 B    fp32 dst' (BH,N)

  k_h   <<<1024, 256, 0, stream>>>(x, W, hT_ws, adj);
  k_sd  <<<256,  256, 0, stream>>>(hT_ws, a_src, a_dst, src_ws, dst_ws, adj);
  k_attn<<<512,  512, 0, stream>>>(adj, hT_ws, src_ws, dst_ws, ao_ws);
  k_out <<<1024, 256, 0, stream>>>(ao_ws, Wo, bo, x, gamma, beta, d_out, adj);
}

// Round 14
// 152.705 us; speedup vs baseline: 1.2847x; 1.2847x over previous
//
#include <hip/hip_runtime.h>

typedef short bf16x8 __attribute__((ext_vector_type(8)));   // 8 bf16 in 4 VGPRs
typedef float f32x4  __attribute__((ext_vector_type(4)));
typedef float f32x2  __attribute__((ext_vector_type(2)));
typedef int   i32x4  __attribute__((ext_vector_type(4)));
typedef unsigned int u32x2 __attribute__((ext_vector_type(2)));

#define DEV static __device__ __forceinline__
#define LOG2E 1.4426950408889634f

DEV float bfu_to_f(unsigned short s) { return __builtin_bit_cast(float, (unsigned int)s << 16); }
DEV unsigned short f_to_bf(float f) {                 // RNE fp32 -> bf16
  unsigned int u = __builtin_bit_cast(unsigned int, f);
  u += 0x7fffu + ((u >> 16) & 1u);
  return (unsigned short)(u >> 16);
}
DEV unsigned int pack_bf_rne(float lo, float hi) {
  return (unsigned int)f_to_bf(lo) | ((unsigned int)f_to_bf(hi) << 16);
}
// guaranteed-native exp2 (single v_exp_f32)
DEV float nexp2(float x) {
#if __has_builtin(__builtin_amdgcn_exp2f)
  return __builtin_amdgcn_exp2f(x);
#else
  return exp2f(x);
#endif
}
// fp8 e4m3 pack/unpack (OCP on gfx950). Selector must be an ICE -> template param.
template<bool HI> DEV unsigned int pk_fp8(float a, float b, unsigned int old) {
  return __builtin_amdgcn_cvt_pk_fp8_f32(a, b, old, HI);
}
template<int W> DEV f32x2 upk_fp8(unsigned int w) {
  auto r = __builtin_amdgcn_cvt_pk_f32_fp8(w, W);
  f32x2 o; o[0] = r[0]; o[1] = r[1]; return o;
}

// dtype discriminator: adj[0][0] == 1.0 exactly. fp32 word0 == 0x3F800000;
// bf16 word0 low halfword = 0x3F80 != 0 -> never equal.
DEV bool detect_f32(const void* adj) { return ((const float*)adj)[0] == 1.0f; }

template<bool F32> DEV float ldS(const void* p, size_t i) {
  if constexpr (F32) return ((const float*)p)[i];
  else               return bfu_to_f(((const unsigned short*)p)[i]);
}
template<bool F32> DEV void ld8f(const void* p, size_t i, float* o) {
  if constexpr (F32) {
    const float* f = (const float*)p + i;
    f32x4 a = *(const f32x4*)f, b = *(const f32x4*)(f + 4);
    o[0]=a[0]; o[1]=a[1]; o[2]=a[2]; o[3]=a[3];
    o[4]=b[0]; o[5]=b[1]; o[6]=b[2]; o[7]=b[3];
  } else {
    i32x4 w = *(const i32x4*)((const unsigned short*)p + i);
#pragma unroll
    for (int k = 0; k < 4; ++k) {
      unsigned int u = (unsigned int)w[k];
      o[2*k]   = __builtin_bit_cast(float, u << 16);
      o[2*k+1] = __builtin_bit_cast(float, u & 0xffff0000u);
    }
  }
}
template<bool F32> DEV bf16x8 ldfrag(const void* p, size_t i) {
  if constexpr (F32) {
    float o[8]; ld8f<true>(p, i, o);
    union { bf16x8 v; unsigned short u[8]; } r;
#pragma unroll
    for (int k = 0; k < 8; ++k) r.u[k] = f_to_bf(o[k]);
    return r.v;
  } else {
    return __builtin_bit_cast(bf16x8, *(const i32x4*)((const unsigned short*)p + i));
  }
}

// ---------------- Kernel 0: adj -> fp8 e4m3 (handles fp32 or bf16 input) ----------
__global__ __launch_bounds__(256) void k_prep(const void* __restrict__ adj,
                                              unsigned char* __restrict__ adjf) {
  const size_t i0 = ((size_t)blockIdx.x * 256 + threadIdx.x) * 8;   // 4M elems total
  u32x2 o;
  if (detect_f32(adj)) {
    const float* a = (const float*)adj + i0;
    f32x4 v0 = *(const f32x4*)a, v1 = *(const f32x4*)(a + 4);
    o[0] = pk_fp8<true>(v0[2], v0[3], pk_fp8<false>(v0[0], v0[1], 0u));
    o[1] = pk_fp8<true>(v1[2], v1[3], pk_fp8<false>(v1[0], v1[1], 0u));
  } else {
    i32x4 w = *(const i32x4*)((const unsigned short*)adj + i0);
    float f[8];
#pragma unroll
    for (int k = 0; k < 4; ++k) {
      unsigned int u = (unsigned int)w[k];
      f[2*k]   = __builtin_bit_cast(float, u << 16);
      f[2*k+1] = __builtin_bit_cast(float, u & 0xffff0000u);
    }
    o[0] = pk_fp8<true>(f[2], f[3], pk_fp8<false>(f[0], f[1], 0u));
    o[1] = pk_fp8<true>(f[6], f[7], pk_fp8<false>(f[4], f[5], 0u));
  }
  *(u32x2*)(adjf + i0) = o;
}

// ---------------- Kernel 1: hT[(b*4+hh)*32+d][n] = (x@W^T) transposed, fp8 ----------
template<bool F32> DEV void k_h_body(const void* __restrict__ x, const void* __restrict__ W,
                                     unsigned char* __restrict__ hT,
                                     unsigned short (&t_s)[16][136]) {
  const int tid = threadIdx.x, lane = tid & 63, wave = tid >> 6;
  const int nt = blockIdx.x >> 3, ct = blockIdx.x & 7;    // 128 nt x 8 ct
  const int m = lane & 15, q = lane >> 4;
  bf16x8 wf[4];
#pragma unroll
  for (int k = 0; k < 4; ++k)
    wf[k] = ldfrag<F32>(W, (size_t)(ct * 16 + m) * 128 + q * 8 + k * 32);
#pragma unroll
  for (int s = 0; s < 2; ++s) {
    const int nsub = wave * 2 + s;
    const size_t xr = (size_t)(nt * 128 + nsub * 16 + m) * 128 + q * 8;
    f32x4 acc = {0.f, 0.f, 0.f, 0.f};
#pragma unroll
    for (int k = 0; k < 4; ++k)
      acc = __builtin_amdgcn_mfma_f32_16x16x32_bf16(ldfrag<F32>(x, xr + k * 32), wf[k],
                                                    acc, 0, 0, 0);
    u32x2 w2; w2[0] = pack_bf_rne(acc[0], acc[1]); w2[1] = pack_bf_rne(acc[2], acc[3]);
    *(u32x2*)&t_s[m][nsub * 16 + q * 4] = w2;
  }
  __syncthreads();
  const int row = tid >> 4, c8 = tid & 15;
  const int chg = ct * 16 + row, hh = chg >> 5, dloc = chg & 31;
  const int ng = nt * 128 + c8 * 8, b = ng >> 11, nl = ng & 2047;
  i32x4 v = *(const i32x4*)&t_s[row][c8 * 8];       // 8 bf16
  float f[8];
#pragma unroll
  for (int k = 0; k < 4; ++k) {
    unsigned int u = (unsigned int)v[k];
    f[2*k]   = __builtin_bit_cast(float, u << 16);
    f[2*k+1] = __builtin_bit_cast(float, u & 0xffff0000u);
  }
  u32x2 o;
  o[0] = pk_fp8<true>(f[2], f[3], pk_fp8<false>(f[0], f[1], 0u));
  o[1] = pk_fp8<true>(f[6], f[7], pk_fp8<false>(f[4], f[5], 0u));
  *(u32x2*)(hT + ((size_t)((b * 4 + hh) * 32 + dloc)) * 2048 + nl) = o;
}
__global__ __launch_bounds__(256) void k_h(const void* x, const void* W,
                                           unsigned char* hT, const void* adj) {
  __shared__ __align__(16) unsigned short t_s[16][136];   // shared across both instantiations
  if (detect_f32(adj)) k_h_body<true>(x, W, hT, t_s); else k_h_body<false>(x, W, hT, t_s);
}

// ---------------- Kernel 1b: src/dst projections (pre-scaled by log2e) ----------------
template<bool F32> DEV void k_sd_body(const unsigned char* __restrict__ hT,
                                      const void* __restrict__ a_src, const void* __restrict__ a_dst,
                                      float* __restrict__ srcv, float* __restrict__ dstv) {
  const int t = blockIdx.x * 256 + threadIdx.x;      // (bh, n), n fastest
  const int n = t & 2047, bh = t >> 11, hh = bh & 3;
  const unsigned char* col = hT + (size_t)bh * 32 * 2048 + n;
  float s = 0.f, d = 0.f;
#pragma unroll
  for (int dd = 0; dd < 32; ++dd) {
    const float v = __builtin_amdgcn_cvt_f32_fp8((int)col[(size_t)dd * 2048], 0);
    s += v * ldS<F32>(a_src, hh * 32 + dd);
    d += v * ldS<F32>(a_dst, hh * 32 + dd);
  }
  srcv[t] = s * LOG2E; dstv[t] = d * LOG2E;          // exp(x) = exp2(x*log2e)
}
__global__ __launch_bounds__(256) void k_sd(const unsigned char* hT, const void* a_src,
                                            const void* a_dst, float* srcv, float* dstv,
                                            const void* adj) {
  if (detect_f32(adj)) k_sd_body<true>(hT, a_src, a_dst, srcv, dstv);
  else                 k_sd_body<false>(hT, a_src, a_dst, srcv, dstv);
}

// ---------------- Kernel 2: fp8 j-split flash GAT attention ----------------
// Block = 512 thr = 1 bh x 64 i-rows: 8 waves = 4 i-tiles x 2 j-halves; grid = 32 bh x
// 32 i64 = 1024 blocks = 4 blocks/CU (fills 32 waves/CU at VGPR<=64). adj read as
// pre-converted fp8 (k_prep); vt fp8 from hT; dst' f32 chunk. All LDS double-buffered,
// ONE barrier per 128-j chunk. den on the MFMA pipe (ones-A). j-half partials merged
// via LDS epilogue reduction (+1 barrier).
struct SmemAttn {
  unsigned char adj[2][64][144];   // 18432 B [buf][i-local][j]
  unsigned char vt[2][32][144];    //  9216 B [buf][d][j]
  float dst[2][128];               //  1024 B [buf][j]
};                                 // 28672 B -> 5 blocks/CU by LDS

__global__ __launch_bounds__(512, 4) void k_attn(const unsigned char* __restrict__ adjf,
                                                 const unsigned char* __restrict__ hT,
                                                 const float* __restrict__ srcv,
                                                 const float* __restrict__ dstv,
                                                 unsigned short* __restrict__ ao) {
  __shared__ __align__(16) SmemAttn sm;
  const int tid = threadIdx.x, lane = tid & 63, wave = tid >> 6;
  const int bh = blockIdx.x & 31, i64 = blockIdx.x >> 5;   // bh-fast: 32 blocks share adj rows
  const int b = bh >> 2, hh = bh & 3;
  const int m = lane & 15, q = lane >> 4;
  const int i0 = i64 * 64;
  const int itile = wave >> 1, jh = wave & 1;
  const int il = itile * 16 + m;                           // lane's local i-row (0..63)

  // staging maps (512 threads)
  const int arow = tid >> 3, acol = (tid & 7) * 16;        // adj: 64 rows x 8 thr x 16 fp8
  const int vd = tid >> 4, vcol = (tid & 15) * 8;          // vt: 32 d x 16 thr x 8 fp8
  const bool dstg = (tid & 15) == 0;
  const int dj = (tid >> 4) * 4;                           // dst: 32 stagers x 4 f32

  const unsigned char* ap = adjf + (size_t)(i0 + arow) * 2048 + acol;
  const unsigned char* vp = hT + ((size_t)bh * 32 + vd) * 2048 + vcol;
  const float* dp = dstv + (size_t)bh * 2048 + dj;

  i32x4 ar; u32x2 vr; f32x4 dr;

  // ---- prologue: stage chunk 0 into buf 0 ----
  ar = *(const i32x4*)ap;
  vr = *(const u32x2*)vp;
  if (dstg) dr = *(const f32x4*)dp;
  *(i32x4*)&sm.adj[0][arow][acol] = ar;
  *(u32x2*)&sm.vt[0][vd][vcol] = vr;
  if (dstg) *(f32x4*)&sm.dst[0][dj] = dr;
  __syncthreads();

  const float src_i = srcv[bh * 2048 + i0 + il];
  const f32x2 src2 = {src_i, src_i};
  f32x4 acc0 = {0.f,0.f,0.f,0.f}, acc1 = {0.f,0.f,0.f,0.f};
  f32x4 acc2 = {0.f,0.f,0.f,0.f};                          // den accumulator (ones-A MFMA)
  const long Aones = 0x3838383838383838L;                  // 8x fp8 e4m3 1.0

  for (int c = 0; c < 16; ++c) {
    const int cb = c & 1;
    const bool pf = (c < 15);
    if (pf) {                                   // issue chunk c+1 loads (coalesced)
      const int j1 = (c + 1) * 128;
      ar = *(const i32x4*)(ap + j1);
      vr = *(const u32x2*)(vp + j1);
      if (dstg) dr = *(const f32x4*)(dp + j1);
    }
    // ---- compute: this wave's j-half = 2 x 32-j on buf cb ----
#pragma unroll
    for (int jc = 0; jc < 2; ++jc) {
      const int jq = jh * 64 + jc * 32 + q * 8;
      u32x2 aw = *(const u32x2*)&sm.adj[cb][il][jq];               // 8 fp8
      f32x4 d0 = *(const f32x4*)&sm.dst[cb][jq];
      f32x4 d1 = *(const f32x4*)&sm.dst[cb][jq + 4];
      long A0 = *(const long*)&sm.vt[cb][m][jq];                   // V^T row d=m
      long A1 = *(const long*)&sm.vt[cb][16 + m][jq];              // d=m+16
      f32x2 av0 = upk_fp8<0>(aw[0]), av1 = upk_fp8<1>(aw[0]);
      f32x2 av2 = upk_fp8<0>(aw[1]), av3 = upk_fp8<1>(aw[1]);
      f32x2 dv0; dv0[0] = d0[0]; dv0[1] = d0[1];
      f32x2 dv1; dv1[0] = d0[2]; dv1[1] = d0[3];
      f32x2 dv2; dv2[0] = d1[0]; dv2[1] = d1[1];
      f32x2 dv3; dv3[0] = d1[2]; dv3[1] = d1[3];
      f32x2 sv0 = src2 + dv0, sv1 = src2 + dv1, sv2 = src2 + dv2, sv3 = src2 + dv3;
      f32x2 lv0 = __builtin_elementwise_max(sv0, 0.2f * sv0);      // leaky (pk)
      f32x2 lv1 = __builtin_elementwise_max(sv1, 0.2f * sv1);
      f32x2 lv2 = __builtin_elementwise_max(sv2, 0.2f * sv2);
      f32x2 lv3 = __builtin_elementwise_max(sv3, 0.2f * sv3);
      f32x2 ev0, ev1, ev2, ev3;
      ev0[0] = nexp2(lv0[0]); ev0[1] = nexp2(lv0[1]);
      ev1[0] = nexp2(lv1[0]); ev1[1] = nexp2(lv1[1]);
      ev2[0] = nexp2(lv2[0]); ev2[1] = nexp2(lv2[1]);
      ev3[0] = nexp2(lv3[0]); ev3[1] = nexp2(lv3[1]);
      f32x2 pv0 = av0 * ev0, pv1 = av1 * ev1, pv2 = av2 * ev2, pv3 = av3 * ev3;
      u32x2 bp;
      bp[0] = pk_fp8<true>(pv1[0], pv1[1], pk_fp8<false>(pv0[0], pv0[1], 0u));
      bp[1] = pk_fp8<true>(pv3[0], pv3[1], pk_fp8<false>(pv2[0], pv2[1], 0u));
      const long B = __builtin_bit_cast(long, bp);
      acc0 = __builtin_amdgcn_mfma_f32_16x16x32_fp8_fp8(A0, B, acc0, 0, 0, 0);
      acc1 = __builtin_amdgcn_mfma_f32_16x16x32_fp8_fp8(A1, B, acc1, 0, 0, 0);
      acc2 = __builtin_amdgcn_mfma_f32_16x16x32_fp8_fp8(Aones, B, acc2, 0, 0, 0);
    }
    if (pf) {                                   // write chunk c+1 into the other buffer
      const int nb = cb ^ 1;
      *(i32x4*)&sm.adj[nb][arow][acol] = ar;
      *(u32x2*)&sm.vt[nb][vd][vcol] = vr;
      if (dstg) *(f32x4*)&sm.dst[nb][dj] = dr;
    }
    __syncthreads();
  }

  // ---- merge j-half partials via LDS (reuse sm), then write output ----
  float* red = (float*)&sm;
  const int ridx = (itile * 64 + lane) * 12;               // 48B stride: 16B-aligned stores
  if (jh == 1) {
    *(f32x4*)&red[ridx]     = acc0;
    *(f32x4*)&red[ridx + 4] = acc1;
    red[ridx + 8] = acc2[0];
  }
  __syncthreads();
  if (jh == 0) {
    acc0 += *(const f32x4*)&red[ridx];
    acc1 += *(const f32x4*)&red[ridx + 4];
    const float den = acc2[0] + red[ridx + 8];
    const float inv = 1.f / fmaxf(den, 1e-20f);
    // D: col = m = i, row = q*4+r = d. Lane writes channels q*4..+3 and 16+q*4..+3.
    unsigned short* op = ao + ((size_t)(b * 2048) + i0 + il) * 128 + hh * 32 + q * 4;
    u32x2 w0, w1;
    w0[0] = pack_bf_rne(acc0[0] * inv, acc0[1] * inv);
    w0[1] = pack_bf_rne(acc0[2] * inv, acc0[3] * inv);
    w1[0] = pack_bf_rne(acc1[0] * inv, acc1[1] * inv);
    w1[1] = pack_bf_rne(acc1[2] * inv, acc1[3] * inv);
    *(u32x2*)op        = w0;
    *(u32x2*)(op + 16) = w1;
  }
}

// ---------------- Kernel 3: y = LN(ao @ Wo^T + bo + x) ----------------
template<bool F32> DEV void k_out_body(const unsigned short* __restrict__ ao,
                                       const void* __restrict__ Wo, const void* __restrict__ bo,
                                       const void* __restrict__ x, const void* __restrict__ gamma,
                                       const void* __restrict__ beta, void* __restrict__ out,
                                       float (&y_s)[16][132]) {
  const int tid = threadIdx.x, lane = tid & 63, wave = tid >> 6;
  const int m = lane & 15, q = lane >> 4;
  const int rbase = blockIdx.x * 16;
  bf16x8 af[4];
#pragma unroll
  for (int k = 0; k < 4; ++k)
    af[k] = ldfrag<false>(ao, ((size_t)(rbase + m)) * 128 + q * 8 + k * 32);
  f32x4 acc[2] = {{0.f,0.f,0.f,0.f},{0.f,0.f,0.f,0.f}};
#pragma unroll
  for (int ct = 0; ct < 2; ++ct) {
    const size_t wrow = (size_t)(wave * 32 + ct * 16 + m) * 128 + q * 8;
#pragma unroll
    for (int k = 0; k < 4; ++k)
      acc[ct] = __builtin_amdgcn_mfma_f32_16x16x32_bf16(af[k], ldfrag<F32>(Wo, wrow + k * 32),
                                                        acc[ct], 0, 0, 0);
  }
#pragma unroll
  for (int ct = 0; ct < 2; ++ct) {
    const int c = wave * 32 + ct * 16 + m;
    const float bov = ldS<F32>(bo, c);
#pragma unroll
    for (int r = 0; r < 4; ++r) {
      const int row = q * 4 + r;
      y_s[row][c] = acc[ct][r] + bov + ldS<F32>(x, (size_t)(rbase + row) * 128 + c);
    }
  }
  __syncthreads();
  const int r = tid >> 4, c16 = tid & 15;
  float vals[8], sum = 0.f, sq = 0.f;
#pragma unroll
  for (int k = 0; k < 8; ++k) {
    const float v = y_s[r][c16 * 8 + k];
    vals[k] = v; sum += v; sq += v * v;
  }
#pragma unroll
  for (int msk = 1; msk < 16; msk <<= 1) {
    sum += __shfl_xor(sum, msk, 16);
    sq  += __shfl_xor(sq,  msk, 16);
  }
  const float mu  = sum * (1.f / 128.f);
  const float var = fmaxf(sq * (1.f / 128.f) - mu * mu, 0.f);
  const float rstd = rsqrtf(var + 1e-5f);
  float o[8];
#pragma unroll
  for (int k = 0; k < 8; ++k) {
    const int c = c16 * 8 + k;
    o[k] = (vals[k] - mu) * rstd * ldS<F32>(gamma, c) + ldS<F32>(beta, c);
  }
  const size_t obase = (size_t)(rbase + r) * 128 + c16 * 8;
  if constexpr (F32) {
    float* op = (float*)out + obase;
    f32x4 w0 = {o[0],o[1],o[2],o[3]}, w1 = {o[4],o[5],o[6],o[7]};
    *(f32x4*)op = w0; *(f32x4*)(op + 4) = w1;
  } else {
    union { unsigned short u[8]; i32x4 v; } ob;
#pragma unroll
    for (int k = 0; k < 8; ++k) ob.u[k] = f_to_bf(o[k]);
    *(i32x4*)((unsigned short*)out + obase) = ob.v;
  }
}
__global__ __launch_bounds__(256) void k_out(const unsigned short* ao, const void* Wo,
                                             const void* bo, const void* x, const void* gamma,
                                             const void* beta, void* out, const void* adj) {
  __shared__ __align__(16) float y_s[16][132];   // shared across both instantiations
  if (detect_f32(adj)) k_out_body<true>(ao, Wo, bo, x, gamma, beta, out, y_s);
  else                 k_out_body<false>(ao, Wo, bo, x, gamma, beta, out, y_s);
}

// ---------------- launch ----------------
extern "C" void kernel_launch(void* const* d_in, const int* in_sizes, int n_in,
                              void* d_out, int out_size, void* d_ws, size_t ws_size,
                              hipStream_t stream) {
  const void* x     = d_in[0];
  const void* adj   = d_in[1];
  const void* W     = d_in[2];
  const void* a_src = d_in[3];
  const void* a_dst = d_in[4];
  const void* Wo    = d_in[5];
  const void* bo    = d_in[6];
  const void* gamma = d_in[7];
  const void* beta  = d_in[8];

  char* ws = (char*)d_ws;
  unsigned char*  hT_ws  = (unsigned char*)ws;               // 2,097,152 B  fp8 hT (BH*32, N)
  unsigned short* ao_ws  = (unsigned short*)(ws + 2097152);  // 4,194,304 B  bf16 attn out
  float*          src_ws = (float*)(ws + 6291456);           // 262,144 B    fp32 src' (BH,N)
  float*          dst_ws = (float*)(ws + 6553600);           // 262,144 B    fp32 dst' (BH,N)
  unsigned char*  adjf   = (unsigned char*)(ws + 6815744);   // 4,194,304 B  fp8 adj
                                                             // total 11,010,048 B

  k_prep<<<2048, 256, 0, stream>>>(adj, adjf);
  k_h   <<<1024, 256, 0, stream>>>(x, W, hT_ws, adj);
  k_sd  <<<256,  256, 0, stream>>>(hT_ws, a_src, a_dst, src_ws, dst_ws, adj);
  k_attn<<<1024, 512, 0, stream>>>(adjf, hT_ws, src_ws, dst_ws, ao_ws);
  k_out <<<1024, 256, 0, stream>>>(ao_ws, Wo, bo, x, gamma, beta, d_out, adj);
}